// Round 1
// baseline (96.454 us; speedup 1.0000x reference)
//
#include <hip/hip_runtime.h>

// Sinkhorn (loop-never-runs degenerate): out[b] = sum_{i,j} c * exp(-10*c),
// c = (xs_i - ys_j)^2 + (x_i - y_j)^2.  B=8, N=M=4096.
//
// Compute-bound (inputs 512 KB, cache-resident). Each thread owns 16 y-pairs
// in registers; rows broadcast via wave-uniform scalar loads.

constexpr int B_ = 8;
constexpr int N_ = 4096;
constexpr int M_ = 4096;
constexpr int THREADS = 256;
constexpr int ROWS_PER_BLOCK = 32;                       // 128 blocks/batch
constexpr int BLOCKS_PER_BATCH = N_ / ROWS_PER_BLOCK;    // 128
constexpr int TOTAL_BLOCKS = B_ * BLOCKS_PER_BATCH;      // 1024

__global__ __launch_bounds__(THREADS) void sinkhorn_kernel(
    const float* __restrict__ x,  const float* __restrict__ y,
    const float* __restrict__ xs, const float* __restrict__ ys,
    float* __restrict__ out)
{
    const int b  = blockIdx.x / BLOCKS_PER_BATCH;
    const int rb = blockIdx.x % BLOCKS_PER_BATCH;
    const int t  = threadIdx.x;

    // Each thread holds 16 y columns (4 x float4), coalesced loads, register-resident.
    const float4* yv4 = reinterpret_cast<const float4*>(y  + (size_t)b * M_);
    const float4* ys4 = reinterpret_cast<const float4*>(ys + (size_t)b * M_);
    float4 yv[4], yg[4];
#pragma unroll
    for (int k = 0; k < 4; ++k) {
        yv[k] = yv4[k * THREADS + t];
        yg[k] = ys4[k * THREADS + t];
    }

    const float* xrow  = x  + (size_t)b * N_ + rb * ROWS_PER_BLOCK;
    const float* xsrow = xs + (size_t)b * N_ + rb * ROWS_PER_BLOCK;

    float acc = 0.0f;
#pragma unroll 4
    for (int r = 0; r < ROWS_PER_BLOCK; ++r) {
        // wave-uniform: compiler scalarizes these to s_load
        const float vx = xrow[r];
        const float sx = xsrow[r];
#pragma unroll
        for (int k = 0; k < 4; ++k) {
            const float4 v4 = yv[k];
            const float4 s4 = yg[k];
            float d0, d1, c;
            d0 = sx - s4.x; d1 = vx - v4.x; c = d0*d0 + d1*d1; acc += c * __expf(-10.0f * c);
            d0 = sx - s4.y; d1 = vx - v4.y; c = d0*d0 + d1*d1; acc += c * __expf(-10.0f * c);
            d0 = sx - s4.z; d1 = vx - v4.z; c = d0*d0 + d1*d1; acc += c * __expf(-10.0f * c);
            d0 = sx - s4.w; d1 = vx - v4.w; c = d0*d0 + d1*d1; acc += c * __expf(-10.0f * c);
        }
    }

    // wave (64-lane) shuffle reduce
#pragma unroll
    for (int off = 32; off > 0; off >>= 1)
        acc += __shfl_down(acc, off, 64);

    __shared__ float wsum[THREADS / 64];
    const int lane = t & 63, wid = t >> 6;
    if (lane == 0) wsum[wid] = acc;
    __syncthreads();
    if (t == 0) {
        float s = 0.0f;
#pragma unroll
        for (int w = 0; w < THREADS / 64; ++w) s += wsum[w];
        atomicAdd(&out[b], s);
    }
}

extern "C" void kernel_launch(void* const* d_in, const int* in_sizes, int n_in,
                              void* d_out, int out_size, void* d_ws, size_t ws_size,
                              hipStream_t stream) {
    const float* x  = (const float*)d_in[0];
    const float* y  = (const float*)d_in[1];
    const float* xs = (const float*)d_in[2];
    const float* ys = (const float*)d_in[3];
    float* out = (float*)d_out;

    // d_out is poisoned 0xAA before every launch — zero it (capture-safe).
    hipMemsetAsync(out, 0, (size_t)out_size * sizeof(float), stream);

    sinkhorn_kernel<<<TOTAL_BLOCKS, THREADS, 0, stream>>>(x, y, xs, ys, out);
}

// Round 2
// 89.263 us; speedup vs baseline: 1.0806x; 1.0806x over previous
//
#include <hip/hip_runtime.h>

// Sinkhorn (loop-never-runs degenerate): out[b] = sum_{i,j} c * exp(-10*c),
// c = (xs_i - ys_j)^2 + (x_i - y_j)^2.  B=8, N=M=4096.
//
// Compute-bound (inputs 512 KB, cache-resident). Each thread owns 16 y-pairs
// in registers; 16 x-row values staged in LDS (broadcast reads).
// exp(-10c) computed as exp2(c * -10*log2e) -> 1 mul + 1 v_exp_f32.

constexpr int B_ = 8;
constexpr int N_ = 4096;
constexpr int M_ = 4096;
constexpr int THREADS = 256;
constexpr int ROWS_PER_BLOCK = 16;                       // 256 blocks/batch
constexpr int BLOCKS_PER_BATCH = N_ / ROWS_PER_BLOCK;    // 256
constexpr int TOTAL_BLOCKS = B_ * BLOCKS_PER_BATCH;      // 2048 -> 8 blocks/CU

__global__ __launch_bounds__(THREADS, 8) void sinkhorn_kernel(
    const float* __restrict__ x,  const float* __restrict__ y,
    const float* __restrict__ xs, const float* __restrict__ ys,
    float* __restrict__ out)
{
    const int b  = blockIdx.x >> 8;    // / BLOCKS_PER_BATCH
    const int rb = blockIdx.x & 255;   // % BLOCKS_PER_BATCH
    const int t  = threadIdx.x;

    // Stage this block's 16 x-rows in LDS (wave-uniform broadcast reads later).
    __shared__ float s_xv[ROWS_PER_BLOCK];
    __shared__ float s_xs[ROWS_PER_BLOCK];
    const float* xrow  = x  + (size_t)b * N_ + rb * ROWS_PER_BLOCK;
    const float* xsrow = xs + (size_t)b * N_ + rb * ROWS_PER_BLOCK;
    if (t < ROWS_PER_BLOCK) {
        s_xv[t] = xrow[t];
        s_xs[t] = xsrow[t];
    }

    // Each thread holds 16 y columns (4 x float4), coalesced, register-resident.
    const float4* yv4 = reinterpret_cast<const float4*>(y  + (size_t)b * M_);
    const float4* ys4 = reinterpret_cast<const float4*>(ys + (size_t)b * M_);
    float4 yv[4], yg[4];
#pragma unroll
    for (int k = 0; k < 4; ++k) {
        yv[k] = yv4[k * THREADS + t];
        yg[k] = ys4[k * THREADS + t];
    }
    __syncthreads();

    const float K = -14.426950408889634f;  // -10 * log2(e)
    float acc0 = 0.0f, acc1 = 0.0f;

#pragma unroll 4
    for (int r = 0; r < ROWS_PER_BLOCK; ++r) {
        const float vx = s_xv[r];   // LDS broadcast
        const float sx = s_xs[r];
#pragma unroll
        for (int k = 0; k < 4; ++k) {
            const float4 v4 = yv[k];
            const float4 s4 = yg[k];
            float d0, d1, c;
            d0 = sx - s4.x; d1 = vx - v4.x; c = d0*d0 + d1*d1;
            acc0 += c * __builtin_amdgcn_exp2f(c * K);
            d0 = sx - s4.y; d1 = vx - v4.y; c = d0*d0 + d1*d1;
            acc1 += c * __builtin_amdgcn_exp2f(c * K);
            d0 = sx - s4.z; d1 = vx - v4.z; c = d0*d0 + d1*d1;
            acc0 += c * __builtin_amdgcn_exp2f(c * K);
            d0 = sx - s4.w; d1 = vx - v4.w; c = d0*d0 + d1*d1;
            acc1 += c * __builtin_amdgcn_exp2f(c * K);
        }
    }
    float acc = acc0 + acc1;

    // wave (64-lane) shuffle reduce
#pragma unroll
    for (int off = 32; off > 0; off >>= 1)
        acc += __shfl_down(acc, off, 64);

    __shared__ float wsum[THREADS / 64];
    const int lane = t & 63, wid = t >> 6;
    if (lane == 0) wsum[wid] = acc;
    __syncthreads();
    if (t == 0) {
        float s = 0.0f;
#pragma unroll
        for (int w = 0; w < THREADS / 64; ++w) s += wsum[w];
        atomicAdd(&out[b], s);
    }
}

extern "C" void kernel_launch(void* const* d_in, const int* in_sizes, int n_in,
                              void* d_out, int out_size, void* d_ws, size_t ws_size,
                              hipStream_t stream) {
    const float* x  = (const float*)d_in[0];
    const float* y  = (const float*)d_in[1];
    const float* xs = (const float*)d_in[2];
    const float* ys = (const float*)d_in[3];
    float* out = (float*)d_out;

    // d_out is poisoned 0xAA before every launch — zero it (capture-safe).
    hipMemsetAsync(out, 0, (size_t)out_size * sizeof(float), stream);

    sinkhorn_kernel<<<TOTAL_BLOCKS, THREADS, 0, stream>>>(x, y, xs, ys, out);
}